// Round 1
// baseline (406.191 us; speedup 1.0000x reference)
//
#include <hip/hip_runtime.h>
#include <hip/hip_bf16.h>

// Problem constants (B=16, N=8192, D=256, H=128, 64 parcels x top-32)
// Dtype model (round-3 evidence): inputs FLOAT32, outputs FLOAT32.
//   Output 0: selected_patches f32[16,2048,256]  elements [0, 8388608)
//   Output 1: all_selected_indices -> f32        elements [8388608, 8421376)
//   Output 2: importance_logits f32[16,8192]     elements [8421376, 8552448)
#define NB 16
#define NN 8192
#define ND 256
#define NH 128
#define NPARCEL 64
#define KSEL 32

typedef __attribute__((ext_vector_type(8))) short short8;   // 8 bf16 lanes (4 VGPRs)
typedef __attribute__((ext_vector_type(4))) float floatx4;  // MFMA C/D
typedef __attribute__((ext_vector_type(4))) float f32x4;

// f32 -> bf16 (RNE) bit trick; finite inputs only
__device__ __forceinline__ unsigned short f2b(float x) {
    unsigned u = __builtin_bit_cast(unsigned, x);
    u += 0x7fffu + ((u >> 16) & 1u);
    return (unsigned short)(u >> 16);
}
__device__ __forceinline__ float b2f(unsigned short h) {
    return __builtin_bit_cast(float, (unsigned)h << 16);
}

// ---------------------------------------------------------------------------
// Scratch aliased into out_sel (f32 rows of 1024 B; region dead until gather):
//   z    f32[131072]  elements [0,      131072) = rows [0,   512)
//   sel  i32[32768]   elements [131072, 163840) = rows [512, 640)
//   W1Th u16[32768]   elements [163840, 180224) = rows [640, 704)
//   W1Tl u16[32768]   elements [180224, 196608) = rows [704, 768)
// Stream order serializes kernels; only sel must survive into the gather ->
// gather1 skips rows [512,640), gather2 (one block) LDS-stages then covers
// them. d_ws unused.

// ---------------------------------------------------------------------------
// Kernel 0: W1 f32 [256,128] -> transposed split-bf16 planes [128,256].
__global__ __launch_bounds__(256) void k_prep(const float* __restrict__ W1,
                                              unsigned short* __restrict__ W1Th,
                                              unsigned short* __restrict__ W1Tl) {
    int i = blockIdx.x * 256 + threadIdx.x;   // 32768
    int k = i >> 7;        // 0..255
    int h = i & 127;       // 0..127
    float w = W1[i];
    unsigned short hi = f2b(w);
    float r = w - b2f(hi);
    W1Th[h * ND + k] = hi;
    W1Tl[h * ND + k] = f2b(r);
}

// ---------------------------------------------------------------------------
// Kernel 1: logits = relu(X@W1+b1)@W2+b2 with split-bf16 MFMA (hh+hl+lh),
// ~1e-6-accurate f32 logits (top-k rank stability vs the f32 reference).
//
// Round-4 restructure (latency-bound fix): the old loop kept bh[8]+bl[8]
// (64 VGPRs) live across both rowgroup passes on top of acc (64 VGPRs),
// blowing the 108-reg allocation -> the allocator recycled load-dest regs
// and serialized every global load (all pipes ~9% busy, ~32K cy per k0
// iteration). Now B fragments are consumed immediately per nt (live B = 8
// regs) and the k0 x nt loops are fully unrolled so the scheduler pipelines
// the 16 independent B loads and hoists next-iteration A loads.
// Accumulation order per acc element is unchanged (hh, hl, lh per k0) ->
// bitwise-identical logits to the passing kernel.
//
// Wave = 2 rowgroups x 16 rows; block = 4 waves = 128 rows; each block
// processes 2 row-tiles (grid-stride) -> grid = 512 blocks (balanced for
// 2-4 blocks/CU residency regardless of final VGPR count).
__global__ __launch_bounds__(256) void k_mlp(const float* __restrict__ feat,
                                             const unsigned short* __restrict__ W1Th,
                                             const unsigned short* __restrict__ W1Tl,
                                             const float* __restrict__ b1,
                                             const float* __restrict__ W2,
                                             const float* __restrict__ b2,
                                             const float* __restrict__ gum,
                                             float* __restrict__ z,
                                             float* __restrict__ out_logit) {
    const int wave = threadIdx.x >> 6;
    const int lane = threadIdx.x & 63;
    const int quad = lane >> 4;
    const int m    = lane & 15;

    const unsigned short* bhb = W1Th + m * ND + quad * 8;
    const unsigned short* blb = W1Tl + m * ND + quad * 8;
    const float b2v = b2[0];

#pragma unroll 1
    for (int t = 0; t < 2; ++t) {
        const int wavebase = (blockIdx.x + t * 512) * 128 + wave * 32;
        const float* ap0 = feat + (size_t)(wavebase + m) * ND + quad * 8;
        const float* ap1 = ap0 + 16 * ND;

        floatx4 acc[2][8];
#pragma unroll
        for (int rg = 0; rg < 2; ++rg)
#pragma unroll
            for (int nt = 0; nt < 8; ++nt) acc[rg][nt] = (floatx4){0.f, 0.f, 0.f, 0.f};

#pragma unroll
        for (int k0 = 0; k0 < ND; k0 += 32) {
            // A for both rowgroups of this k0 (32 B/lane each)
            f32x4 a00 = *(const f32x4*)(ap0 + k0);
            f32x4 a01 = *(const f32x4*)(ap0 + k0 + 4);
            f32x4 a10 = *(const f32x4*)(ap1 + k0);
            f32x4 a11 = *(const f32x4*)(ap1 + k0 + 4);
            short8 ah0, al0, ah1, al1;
#pragma unroll
            for (int j = 0; j < 8; ++j) {
                float x0 = (j < 4) ? a00[j] : a01[j - 4];
                unsigned short h0 = f2b(x0);
                ah0[j] = (short)h0;
                al0[j] = (short)f2b(x0 - b2f(h0));
                float x1 = (j < 4) ? a10[j] : a11[j - 4];
                unsigned short h1 = f2b(x1);
                ah1[j] = (short)h1;
                al1[j] = (short)f2b(x1 - b2f(h1));
            }
#pragma unroll
            for (int nt = 0; nt < 8; ++nt) {
                short8 bh = *(const short8*)(bhb + nt * 16 * ND + k0);
                short8 bl = *(const short8*)(blb + nt * 16 * ND + k0);
                // per-acc-element order unchanged: hh, hl, lh
                acc[0][nt] = __builtin_amdgcn_mfma_f32_16x16x32_bf16(ah0, bh, acc[0][nt], 0, 0, 0);
                acc[0][nt] = __builtin_amdgcn_mfma_f32_16x16x32_bf16(ah0, bl, acc[0][nt], 0, 0, 0);
                acc[0][nt] = __builtin_amdgcn_mfma_f32_16x16x32_bf16(al0, bh, acc[0][nt], 0, 0, 0);
                acc[1][nt] = __builtin_amdgcn_mfma_f32_16x16x32_bf16(ah1, bh, acc[1][nt], 0, 0, 0);
                acc[1][nt] = __builtin_amdgcn_mfma_f32_16x16x32_bf16(ah1, bl, acc[1][nt], 0, 0, 0);
                acc[1][nt] = __builtin_amdgcn_mfma_f32_16x16x32_bf16(al1, bh, acc[1][nt], 0, 0, 0);
            }
        }

        // Epilogue (f32): relu(acc + b1) * W2, reduce over hidden, + b2.
#pragma unroll
        for (int rg = 0; rg < 2; ++rg) {
            float s[4] = {0.f, 0.f, 0.f, 0.f};
#pragma unroll
            for (int nt = 0; nt < 8; ++nt) {
                float b1f = b1[nt * 16 + m];
                float w2f = W2[nt * 16 + m];
#pragma unroll
                for (int r = 0; r < 4; ++r) {
                    float h = acc[rg][nt][r] + b1f;
                    s[r] += (h > 0.f ? h : 0.f) * w2f;
                }
            }
#pragma unroll
            for (int off = 1; off < 16; off <<= 1) {
#pragma unroll
                for (int r = 0; r < 4; ++r) s[r] += __shfl_xor(s[r], off, 64);
            }
            if (m == 0) {
                int rowbase = wavebase + rg * 16 + quad * 4;
#pragma unroll
                for (int r = 0; r < 4; ++r) {
                    int row = rowbase + r;
                    float logit = s[r] + b2v;
                    out_logit[row] = logit;
                    z[row] = logit + gum[row];   // softmax monotone in z: top-k on z
                }
            }
        }
    }
}

// ---------------------------------------------------------------------------
// Kernel 2: per (batch,parcel) top-32 of the 128 candidates {p, p+64, ...}.
// Iterative wave-argmax; tie -> smaller index (jax.lax.top_k stable order).
// Indices clamped into [0,8191] so garbage can never fault the gather.
__global__ __launch_bounds__(64) void k_topk(const float* __restrict__ z,
                                             int* __restrict__ sel,
                                             float* __restrict__ out_idx) {
    const int b = blockIdx.x >> 6;
    const int p = blockIdx.x & 63;
    const int l = threadIdx.x;
    const float* zb = z + b * NN;
    int i0 = p + 64 * l;
    int i1 = i0 + 4096;
    float v0 = zb[i0];
    float v1 = zb[i1];
    const int obase = b * (NPARCEL * KSEL) + p * KSEL;

    for (int r = 0; r < KSEL; ++r) {
        float bv; int bi;
        if (v0 > v1 || (v0 == v1 && i0 < i1)) { bv = v0; bi = i0; }
        else                                  { bv = v1; bi = i1; }
#pragma unroll
        for (int off = 1; off < 64; off <<= 1) {
            float ov = __shfl_xor(bv, off, 64);
            int   oi = __shfl_xor(bi, off, 64);
            if (ov > bv || (ov == bv && oi < bi)) { bv = ov; bi = oi; }
        }
        if      (bi == i0) { v0 = -__builtin_inff(); i0 = 0x7fffffff; }
        else if (bi == i1) { v1 = -__builtin_inff(); i1 = 0x7fffffff; }
        if (l == r) {
            int safe = bi & (NN - 1);            // never OOB, even on garbage z
            sel[obase + r] = safe;
            out_idx[obase + r] = (float)safe;    // exact f32 integer
        }
    }
}

// ---------------------------------------------------------------------------
// Kernel 3a: gather f32 patch rows -> f32 out rows (mask value == 1.0).
// 64 lanes/row: lane moves one float4 (16 B); 4 rows/block; 8192 blocks.
// Skips out rows [512,640) which still host sel (kernel 3b's job).
__global__ __launch_bounds__(256) void k_gather1(const float* __restrict__ patches,
                                                 const int* __restrict__ sel,
                                                 float* __restrict__ out) {
    const int t = threadIdx.x;
    const int g = t >> 6;
    const int l = t & 63;
    const int rowk = blockIdx.x * 4 + g;          // 0..32767
    if (rowk >= 512 && rowk < 640) return;        // sel-host rows -> gather2
    const int b = rowk >> 11;                     // /2048
    const int idx = sel[rowk] & (NN - 1);
    f32x4 v = *((const f32x4*)(patches + ((size_t)b * NN + idx) * ND) + l);
    *((f32x4*)(out + (size_t)rowk * ND) + l) = v;
}

// Kernel 3b: single block; stage the 128 sel entries for rows [512,640)
// through LDS, then overwrite those rows (all batch 0).
__global__ __launch_bounds__(256) void k_gather2(const float* __restrict__ patches,
                                                 const int* __restrict__ sel,
                                                 float* __restrict__ out) {
    __shared__ int sel_s[128];
    const int t = threadIdx.x;
    if (t < 128) sel_s[t] = sel[512 + t] & (NN - 1);
    __syncthreads();
    const int g = t >> 6;      // 4 rows per iteration
    const int l = t & 63;
#pragma unroll 4
    for (int it = 0; it < 32; ++it) {
        const int r = it * 4 + g;                 // 0..127
        const int rowk = 512 + r;                 // batch 0 rows
        const int idx = sel_s[r];
        f32x4 v = *((const f32x4*)(patches + (size_t)idx * ND) + l);
        *((f32x4*)(out + (size_t)rowk * ND) + l) = v;
    }
}

// ---------------------------------------------------------------------------
extern "C" void kernel_launch(void* const* d_in, const int* in_sizes, int n_in,
                              void* d_out, int out_size, void* d_ws, size_t ws_size,
                              hipStream_t stream) {
    const float* patches = (const float*)d_in[0];
    const float* feat    = (const float*)d_in[1];
    const float* W1      = (const float*)d_in[2];
    const float* b1      = (const float*)d_in[3];
    const float* W2      = (const float*)d_in[4];
    const float* b2      = (const float*)d_in[5];
    const float* gum     = (const float*)d_in[6];
    // d_in[7] = lookup: structurally arange(N) % 64 — exploited.

    float* out       = (float*)d_out;
    float* out_sel   = out;                       // 8,388,608 f32
    float* out_idx   = out + 8388608;             // 32,768 f32 (exact ints)
    float* out_logit = out + 8388608 + 32768;     // 131,072 f32

    // scratch aliased into the (not-yet-written) out_sel region
    float*          z    = out_sel;                              // elements [0, 131072)
    int*            sel  = (int*)(out_sel + 131072);             // elements [131072, 163840)
    unsigned short* W1Th = (unsigned short*)(out_sel + 163840);  // 64 KB
    unsigned short* W1Tl = (unsigned short*)(out_sel + 180224);  // 64 KB

    k_prep<<<128, 256, 0, stream>>>(W1, W1Th, W1Tl);
    k_mlp<<<(NB * NN) / 128 / 2, 256, 0, stream>>>(feat, W1Th, W1Tl, b1, W2, b2, gum, z, out_logit);
    k_topk<<<NB * NPARCEL, 64, 0, stream>>>(z, sel, out_idx);
    k_gather1<<<(NB * NPARCEL * KSEL) / 4, 256, 0, stream>>>(patches, sel, out_sel);
    k_gather2<<<1, 256, 0, stream>>>(patches, sel, out_sel);
}

// Round 2
// 341.130 us; speedup vs baseline: 1.1907x; 1.1907x over previous
//
#include <hip/hip_runtime.h>
#include <hip/hip_bf16.h>

// Problem constants (B=16, N=8192, D=256, H=128, 64 parcels x top-32)
// Dtype model: inputs FLOAT32, outputs FLOAT32.
//   Output 0: selected_patches f32[16,2048,256]  elements [0, 8388608)
//   Output 1: all_selected_indices -> f32        elements [8388608, 8421376)
//   Output 2: importance_logits f32[16,8192]     elements [8421376, 8552448)
#define NB 16
#define NN 8192
#define ND 256
#define NH 128
#define NPARCEL 64
#define KSEL 32

typedef __attribute__((ext_vector_type(8))) short short8;   // 8 bf16 lanes (4 VGPRs)
typedef __attribute__((ext_vector_type(4))) float floatx4;  // MFMA C/D
typedef __attribute__((ext_vector_type(4))) float f32x4;

// f32 -> bf16 (RNE) bit trick; finite inputs only
__device__ __forceinline__ unsigned short f2b(float x) {
    unsigned u = __builtin_bit_cast(unsigned, x);
    u += 0x7fffu + ((u >> 16) & 1u);
    return (unsigned short)(u >> 16);
}
__device__ __forceinline__ float b2f(unsigned short h) {
    return __builtin_bit_cast(float, (unsigned)h << 16);
}

// ---------------------------------------------------------------------------
// Scratch aliased into out_sel (dead until the fused gather, which is the
// last kernel and overwrites every row):
//   W1Th u16[32768]  elements [0,     16384) = rows [0,  64)
//   W1Tl u16[32768]  elements [16384, 32768) = rows [64, 128)
// z/sel scratch is GONE: the fused top-k recomputes z = logit + gumbel from
// out_logit (exact f32 round-trip -> bitwise-identical z) and keeps sel in
// registers. d_ws unused.

// ---------------------------------------------------------------------------
// Kernel 0: W1 f32 [256,128] -> transposed split-bf16 planes [128,256].
__global__ __launch_bounds__(256) void k_prep(const float* __restrict__ W1,
                                              unsigned short* __restrict__ W1Th,
                                              unsigned short* __restrict__ W1Tl) {
    int i = blockIdx.x * 256 + threadIdx.x;   // 32768
    int k = i >> 7;        // 0..255
    int h = i & 127;       // 0..127
    float w = W1[i];
    unsigned short hi = f2b(w);
    float r = w - b2f(hi);
    W1Th[h * ND + k] = hi;
    W1Tl[h * ND + k] = f2b(r);
}

// ---------------------------------------------------------------------------
// Kernel 1: logits = relu(X@W1+b1)@W2+b2 with split-bf16 MFMA (hh+hl+lh),
// ~1e-6-accurate f32 logits (top-k rank stability vs the f32 reference).
//
// Round-2 structure (register-pressure middle ground):
//  - Round 0: bh[8]+bl[8] (64 VGPRs) live across both rowgroups -> allocator
//    recycled load-dest regs at 108 VGPR -> every load serialized (~32K cy
//    per k0 iter, all pipes 9% busy).
//  - Round 1: full k0 unroll -> 256 VGPR + 107 MB scratch spills (WRITE_SIZE
//    exploded), 161 us.
//  - Now: per-nt immediate B consumption (live B = 8 regs) + ROLLED k0 loop
//    (#pragma unroll 1). Per iteration the scheduler sees 16 independent B
//    loads + 4 A loads; live set ~= acc(64)+A(32)+transients ~= 130 VGPR.
// Accumulation order per acc element unchanged (hh, hl, lh per k0) ->
// bitwise-identical logits to the round-0 passing kernel.
__global__ __launch_bounds__(256) void k_mlp(const float* __restrict__ feat,
                                             const unsigned short* __restrict__ W1Th,
                                             const unsigned short* __restrict__ W1Tl,
                                             const float* __restrict__ b1,
                                             const float* __restrict__ W2,
                                             const float* __restrict__ b2,
                                             float* __restrict__ out_logit) {
    const int wave = threadIdx.x >> 6;
    const int lane = threadIdx.x & 63;
    const int quad = lane >> 4;
    const int m    = lane & 15;
    const int wavebase = blockIdx.x * 128 + wave * 32;

    const unsigned short* bhb = W1Th + m * ND + quad * 8;
    const unsigned short* blb = W1Tl + m * ND + quad * 8;
    const float* ap0 = feat + (size_t)(wavebase + m) * ND + quad * 8;
    const float* ap1 = ap0 + 16 * ND;

    floatx4 acc[2][8];
#pragma unroll
    for (int rg = 0; rg < 2; ++rg)
#pragma unroll
        for (int nt = 0; nt < 8; ++nt) acc[rg][nt] = (floatx4){0.f, 0.f, 0.f, 0.f};

#pragma unroll 1
    for (int k0 = 0; k0 < ND; k0 += 32) {
        // A for both rowgroups of this k0 (32 B/lane each)
        f32x4 a00 = *(const f32x4*)(ap0 + k0);
        f32x4 a01 = *(const f32x4*)(ap0 + k0 + 4);
        f32x4 a10 = *(const f32x4*)(ap1 + k0);
        f32x4 a11 = *(const f32x4*)(ap1 + k0 + 4);
        short8 ah0, al0, ah1, al1;
#pragma unroll
        for (int j = 0; j < 8; ++j) {
            float x0 = (j < 4) ? a00[j] : a01[j - 4];
            unsigned short h0 = f2b(x0);
            ah0[j] = (short)h0;
            al0[j] = (short)f2b(x0 - b2f(h0));
            float x1 = (j < 4) ? a10[j] : a11[j - 4];
            unsigned short h1 = f2b(x1);
            ah1[j] = (short)h1;
            al1[j] = (short)f2b(x1 - b2f(h1));
        }
#pragma unroll
        for (int nt = 0; nt < 8; ++nt) {
            short8 bh = *(const short8*)(bhb + nt * 16 * ND + k0);
            short8 bl = *(const short8*)(blb + nt * 16 * ND + k0);
            // per-acc-element order unchanged: hh, hl, lh
            acc[0][nt] = __builtin_amdgcn_mfma_f32_16x16x32_bf16(ah0, bh, acc[0][nt], 0, 0, 0);
            acc[0][nt] = __builtin_amdgcn_mfma_f32_16x16x32_bf16(ah0, bl, acc[0][nt], 0, 0, 0);
            acc[0][nt] = __builtin_amdgcn_mfma_f32_16x16x32_bf16(al0, bh, acc[0][nt], 0, 0, 0);
            acc[1][nt] = __builtin_amdgcn_mfma_f32_16x16x32_bf16(ah1, bh, acc[1][nt], 0, 0, 0);
            acc[1][nt] = __builtin_amdgcn_mfma_f32_16x16x32_bf16(ah1, bl, acc[1][nt], 0, 0, 0);
            acc[1][nt] = __builtin_amdgcn_mfma_f32_16x16x32_bf16(al1, bh, acc[1][nt], 0, 0, 0);
        }
    }

    // Epilogue (f32): relu(acc + b1) * W2, reduce over hidden, + b2.
    const float b2v = b2[0];
#pragma unroll
    for (int rg = 0; rg < 2; ++rg) {
        float s[4] = {0.f, 0.f, 0.f, 0.f};
#pragma unroll
        for (int nt = 0; nt < 8; ++nt) {
            float b1f = b1[nt * 16 + m];
            float w2f = W2[nt * 16 + m];
#pragma unroll
            for (int r = 0; r < 4; ++r) {
                float h = acc[rg][nt][r] + b1f;
                s[r] += (h > 0.f ? h : 0.f) * w2f;
            }
        }
#pragma unroll
        for (int off = 1; off < 16; off <<= 1) {
#pragma unroll
            for (int r = 0; r < 4; ++r) s[r] += __shfl_xor(s[r], off, 64);
        }
        if (m == 0) {
            int rowbase = wavebase + rg * 16 + quad * 4;
#pragma unroll
            for (int r = 0; r < 4; ++r) {
                int row = rowbase + r;
                out_logit[row] = s[r] + b2v;
            }
        }
    }
}

// ---------------------------------------------------------------------------
// Kernel 2 (fused top-k + gather): one block per (batch,parcel).
// z = logit + gumbel is recomputed from out_logit (exact f32 values -> z is
// bitwise-identical to the old k_mlp-produced z; identical top-k ranks).
// All 4 waves redundantly run the 32-round wave-argmax (same result, runs in
// parallel on 4 SIMDs, no LDS/sync); each wave keeps its 8 row indices in
// statically-indexed registers, then gathers its 8 patch rows.
// Tie -> smaller index (jax.lax.top_k stable order). Indices clamped into
// [0,8191] so garbage can never fault the gather.
__global__ __launch_bounds__(256) void k_topk_gather(const float* __restrict__ logit,
                                                     const float* __restrict__ gum,
                                                     const float* __restrict__ patches,
                                                     float* __restrict__ out_sel,
                                                     float* __restrict__ out_idx) {
    const int b = blockIdx.x >> 6;
    const int p = blockIdx.x & 63;
    const int t = threadIdx.x;
    const int g = t >> 6;      // wave 0..3
    const int l = t & 63;      // lane

    const float* lb = logit + b * NN;
    const float* gb = gum + b * NN;
    int i0 = p + 64 * l;       // candidate set of parcel p: {p + 64*j, j=0..127}
    int i1 = i0 + 4096;
    float v0 = lb[i0] + gb[i0];
    float v1 = lb[i1] + gb[i1];
    const int obase = b * (NPARCEL * KSEL) + p * KSEL;

    int idxs[8];               // statically indexed (unrolled) -> registers
#pragma unroll
    for (int r = 0; r < KSEL; ++r) {
        float bv; int bi;
        if (v0 > v1 || (v0 == v1 && i0 < i1)) { bv = v0; bi = i0; }
        else                                  { bv = v1; bi = i1; }
#pragma unroll
        for (int off = 1; off < 64; off <<= 1) {
            float ov = __shfl_xor(bv, off, 64);
            int   oi = __shfl_xor(bi, off, 64);
            if (ov > bv || (ov == bv && oi < bi)) { bv = ov; bi = oi; }
        }
        // (bv,bi) now uniform across the wave
        if      (bi == i0) { v0 = -__builtin_inff(); i0 = 0x7fffffff; }
        else if (bi == i1) { v1 = -__builtin_inff(); i1 = 0x7fffffff; }
        int safe = bi & (NN - 1);
        if (t == r) out_idx[obase + r] = (float)safe;   // wave 0, lane r
        if ((r & 3) == g) idxs[r >> 2] = safe;          // this wave's rows
    }

    // Gather: wave g handles out rows r = rr*4 + g; 64 lanes x 16 B per row.
#pragma unroll
    for (int rr = 0; rr < 8; ++rr) {
        const int r = rr * 4 + g;
        f32x4 v = *((const f32x4*)(patches + ((size_t)b * NN + idxs[rr]) * ND) + l);
        *((f32x4*)(out_sel + (size_t)(obase + r) * ND) + l) = v;
    }
}

// ---------------------------------------------------------------------------
extern "C" void kernel_launch(void* const* d_in, const int* in_sizes, int n_in,
                              void* d_out, int out_size, void* d_ws, size_t ws_size,
                              hipStream_t stream) {
    const float* patches = (const float*)d_in[0];
    const float* feat    = (const float*)d_in[1];
    const float* W1      = (const float*)d_in[2];
    const float* b1      = (const float*)d_in[3];
    const float* W2      = (const float*)d_in[4];
    const float* b2      = (const float*)d_in[5];
    const float* gum     = (const float*)d_in[6];
    // d_in[7] = lookup: structurally arange(N) % 64 — exploited.

    float* out       = (float*)d_out;
    float* out_sel   = out;                       // 8,388,608 f32
    float* out_idx   = out + 8388608;             // 32,768 f32 (exact ints)
    float* out_logit = out + 8388608 + 32768;     // 131,072 f32

    // scratch aliased into the (not-yet-written) out_sel region
    unsigned short* W1Th = (unsigned short*)(out_sel);           // 64 KB
    unsigned short* W1Tl = (unsigned short*)(out_sel + 16384);   // 64 KB

    k_prep<<<128, 256, 0, stream>>>(W1, W1Th, W1Tl);
    k_mlp<<<(NB * NN) / 128, 256, 0, stream>>>(feat, W1Th, W1Tl, b1, W2, b2, out_logit);
    k_topk_gather<<<NB * NPARCEL, 256, 0, stream>>>(out_logit, gum, patches, out_sel, out_idx);
}

// Round 3
// 308.399 us; speedup vs baseline: 1.3171x; 1.1061x over previous
//
#include <hip/hip_runtime.h>
#include <hip/hip_bf16.h>

// Problem constants (B=16, N=8192, D=256, H=128, 64 parcels x top-32)
// Dtype model: inputs FLOAT32, outputs FLOAT32.
//   Output 0: selected_patches f32[16,2048,256]  elements [0, 8388608)
//   Output 1: all_selected_indices -> f32        elements [8388608, 8421376)
//   Output 2: importance_logits f32[16,8192]     elements [8421376, 8552448)
#define NB 16
#define NN 8192
#define ND 256
#define NH 128
#define NPARCEL 64
#define KSEL 32

typedef __attribute__((ext_vector_type(8))) short short8;   // 8 bf16 lanes (4 VGPRs)
typedef __attribute__((ext_vector_type(4))) float floatx4;  // MFMA C/D
typedef __attribute__((ext_vector_type(4))) float f32x4;

// f32 -> bf16 (RNE) bit trick; finite inputs only
__device__ __forceinline__ unsigned short f2b(float x) {
    unsigned u = __builtin_bit_cast(unsigned, x);
    u += 0x7fffu + ((u >> 16) & 1u);
    return (unsigned short)(u >> 16);
}
__device__ __forceinline__ float b2f(unsigned short h) {
    return __builtin_bit_cast(float, (unsigned)h << 16);
}

// ---------------------------------------------------------------------------
// Scratch aliased into out_sel (dead until the fused gather, which is the
// last kernel and overwrites every row):
//   W1T u16[2][128][256]  elements [0, 32768) f32 = rows [0, 128)
//     plane 0 = hi bf16 plane (transposed), plane 1 = lo plane.
// The fused top-k recomputes z = logit + gumbel from out_logit (exact f32
// round-trip -> bitwise-identical z) and keeps sel in registers. d_ws unused.

// ---------------------------------------------------------------------------
// Kernel 0: W1 f32 [256,128] -> transposed split-bf16 planes [2][128][256].
__global__ __launch_bounds__(256) void k_prep(const float* __restrict__ W1,
                                              unsigned short* __restrict__ W1T) {
    int i = blockIdx.x * 256 + threadIdx.x;   // 32768
    int k = i >> 7;        // 0..255
    int h = i & 127;       // 0..127
    float w = W1[i];
    unsigned short hi = f2b(w);
    float r = w - b2f(hi);
    W1T[h * ND + k] = hi;                     // hi plane
    W1T[32768 + h * ND + k] = f2b(r);         // lo plane
}

// ---------------------------------------------------------------------------
// Kernel 1: logits = relu(X@W1+b1)@W2+b2 with split-bf16 MFMA (hh+hl+lh),
// ~1e-6-accurate f32 logits (top-k rank stability vs the f32 reference).
//
// Round-3 structure (LDS-staged B):
//  - Rounds 0/2 (B from global): allocator pinned VGPR=108, zero headroom ->
//    every per-nt B load was a serialized global round trip (~13K cy/wave).
//  - Round 1 (full unroll): 256 VGPR + 107 MB scratch spills.
//  - Now: W1T staged in a 64 KB LDS buffer in two k-phases (k in [0,128),
//    then [128,256)). B reads become ds_read_b128 at base + nt*4096
//    immediates; compiler pipelines ds_read->MFMA with counted lgkmcnt.
//    XOR swizzle byte^=((h&7)<<4) on write+read: unswizzled, 16 lanes sit in
//    the same 16B column slot at 256B row stride (16-way conflict); swizzled,
//    uniform 8 lanes/slot = the 8-clock wave64 minimum.
//  - A is software-prefetched 1 k0-step ahead. VGPR ~140 is FREE: occupancy
//    is LDS-capped at 2 blocks/CU (launch_bounds(256,2) caps at 256).
// MFMA order per acc element unchanged (hh, hl, lh per k0) -> bitwise-
// identical logits to the round-0/2 passing kernels.
__global__ __launch_bounds__(256, 2) void k_mlp(const float* __restrict__ feat,
                                                const unsigned short* __restrict__ W1T,
                                                const float* __restrict__ b1,
                                                const float* __restrict__ W2,
                                                const float* __restrict__ b2,
                                                float* __restrict__ out_logit) {
    __shared__ f32x4 lds4[4096];             // 64 KB: [plane][h][kk/2 in 16B chunks], swizzled
    unsigned char* lds = (unsigned char*)lds4;

    const int wave = threadIdx.x >> 6;
    const int lane = threadIdx.x & 63;
    const int quad = lane >> 4;
    const int m    = lane & 15;
    const int wavebase = blockIdx.x * 128 + wave * 32;

    const float* ap0 = feat + (size_t)(wavebase + m) * ND + quad * 8;
    const float* ap1 = ap0 + 16 * ND;
    const int swz = (m & 7) << 4;            // read-side XOR (h&7 == m&7 for h=nt*16+m)

    floatx4 acc[2][8];
#pragma unroll
    for (int rg = 0; rg < 2; ++rg)
#pragma unroll
        for (int nt = 0; nt < 8; ++nt) acc[rg][nt] = (floatx4){0.f, 0.f, 0.f, 0.f};

    // A prefetch for k0 = 0
    f32x4 a00 = *(const f32x4*)(ap0);
    f32x4 a01 = *(const f32x4*)(ap0 + 4);
    f32x4 a10 = *(const f32x4*)(ap1);
    f32x4 a11 = *(const f32x4*)(ap1 + 4);

#pragma unroll 1
    for (int ph = 0; ph < 2; ++ph) {
        if (ph) __syncthreads();             // all waves done reading phase-0 B
        // Stage 64 KB: 4096 16B chunks, 16 per thread. Chunk c -> linear dest
        // d = c*16 = pl*32768 + h*256 + cc*16; store at d ^ ((h&7)<<4).
        // Source: W1T[pl][h][ph*128 + cc*8 .. +8) = byte pl*65536 + h*512 +
        // ph*256 + cc*16. Wave writes 1024 consecutive (slot-permuted) bytes
        // per iteration -> conflict-free.
#pragma unroll
        for (int i = 0; i < 16; ++i) {
            int c  = threadIdx.x + i * 256;
            int pl = c >> 11;
            int h  = (c >> 4) & 127;
            f32x4 v = *(const f32x4*)((const unsigned char*)W1T +
                                      pl * 65536 + h * 512 + ph * 256 + (c & 15) * 16);
            *(f32x4*)(lds + ((c * 16) ^ ((h & 7) << 4))) = v;
        }
        __syncthreads();

#pragma unroll 1
        for (int kk = 0; kk < 128; kk += 32) {
            const int k0 = ph * 128 + kk;
            const int kn = (k0 + 32) & 255;  // next k0 (wraps harmlessly on last)
            // prefetch next A while this k0 computes
            f32x4 n00 = *(const f32x4*)(ap0 + kn);
            f32x4 n01 = *(const f32x4*)(ap0 + kn + 4);
            f32x4 n10 = *(const f32x4*)(ap1 + kn);
            f32x4 n11 = *(const f32x4*)(ap1 + kn + 4);

            // convert current A to split bf16
            short8 ah0, al0, ah1, al1;
#pragma unroll
            for (int j = 0; j < 8; ++j) {
                float x0 = (j < 4) ? a00[j] : a01[j - 4];
                unsigned short h0 = f2b(x0);
                ah0[j] = (short)h0;
                al0[j] = (short)f2b(x0 - b2f(h0));
                float x1 = (j < 4) ? a10[j] : a11[j - 4];
                unsigned short h1 = f2b(x1);
                ah1[j] = (short)h1;
                al1[j] = (short)f2b(x1 - b2f(h1));
            }

            // B from LDS: h = nt*16 + m, row 256 B, nt*4096 is an immediate
            const int rb = (m * 256 + quad * 16 + kk * 2) ^ swz;
#pragma unroll
            for (int nt = 0; nt < 8; ++nt) {
                short8 bh = *(const short8*)(lds + (rb + nt * 4096));
                short8 bl = *(const short8*)(lds + (rb + nt * 4096 + 32768));
                // per-acc-element order unchanged: hh, hl, lh
                acc[0][nt] = __builtin_amdgcn_mfma_f32_16x16x32_bf16(ah0, bh, acc[0][nt], 0, 0, 0);
                acc[0][nt] = __builtin_amdgcn_mfma_f32_16x16x32_bf16(ah0, bl, acc[0][nt], 0, 0, 0);
                acc[0][nt] = __builtin_amdgcn_mfma_f32_16x16x32_bf16(al0, bh, acc[0][nt], 0, 0, 0);
                acc[1][nt] = __builtin_amdgcn_mfma_f32_16x16x32_bf16(ah1, bh, acc[1][nt], 0, 0, 0);
                acc[1][nt] = __builtin_amdgcn_mfma_f32_16x16x32_bf16(ah1, bl, acc[1][nt], 0, 0, 0);
                acc[1][nt] = __builtin_amdgcn_mfma_f32_16x16x32_bf16(al1, bh, acc[1][nt], 0, 0, 0);
            }
            a00 = n00; a01 = n01; a10 = n10; a11 = n11;
        }
    }

    // Epilogue (f32): relu(acc + b1) * W2, reduce over hidden, + b2.
    const float b2v = b2[0];
#pragma unroll
    for (int rg = 0; rg < 2; ++rg) {
        float s[4] = {0.f, 0.f, 0.f, 0.f};
#pragma unroll
        for (int nt = 0; nt < 8; ++nt) {
            float b1f = b1[nt * 16 + m];
            float w2f = W2[nt * 16 + m];
#pragma unroll
            for (int r = 0; r < 4; ++r) {
                float h = acc[rg][nt][r] + b1f;
                s[r] += (h > 0.f ? h : 0.f) * w2f;
            }
        }
#pragma unroll
        for (int off = 1; off < 16; off <<= 1) {
#pragma unroll
            for (int r = 0; r < 4; ++r) s[r] += __shfl_xor(s[r], off, 64);
        }
        if (m == 0) {
            int rowbase = wavebase + rg * 16 + quad * 4;
#pragma unroll
            for (int r = 0; r < 4; ++r) {
                int row = rowbase + r;
                out_logit[row] = s[r] + b2v;
            }
        }
    }
}

// ---------------------------------------------------------------------------
// Kernel 2 (fused top-k + gather): one block per (batch,parcel).
// z = logit + gumbel is recomputed from out_logit (exact f32 values -> z is
// bitwise-identical; identical top-k ranks). All 4 waves redundantly run the
// 32-round wave-argmax (same result, in parallel on 4 SIMDs, no LDS/sync);
// each wave keeps its 8 row indices in statically-indexed registers, then
// gathers its 8 patch rows. Tie -> smaller index (jax.lax.top_k stable
// order). Indices clamped into [0,8191] so garbage can never fault.
__global__ __launch_bounds__(256) void k_topk_gather(const float* __restrict__ logit,
                                                     const float* __restrict__ gum,
                                                     const float* __restrict__ patches,
                                                     float* __restrict__ out_sel,
                                                     float* __restrict__ out_idx) {
    const int b = blockIdx.x >> 6;
    const int p = blockIdx.x & 63;
    const int t = threadIdx.x;
    const int g = t >> 6;      // wave 0..3
    const int l = t & 63;      // lane

    const float* lb = logit + b * NN;
    const float* gb = gum + b * NN;
    int i0 = p + 64 * l;       // candidate set of parcel p: {p + 64*j, j=0..127}
    int i1 = i0 + 4096;
    float v0 = lb[i0] + gb[i0];
    float v1 = lb[i1] + gb[i1];
    const int obase = b * (NPARCEL * KSEL) + p * KSEL;

    int idxs[8];               // statically indexed (unrolled) -> registers
#pragma unroll
    for (int r = 0; r < KSEL; ++r) {
        float bv; int bi;
        if (v0 > v1 || (v0 == v1 && i0 < i1)) { bv = v0; bi = i0; }
        else                                  { bv = v1; bi = i1; }
#pragma unroll
        for (int off = 1; off < 64; off <<= 1) {
            float ov = __shfl_xor(bv, off, 64);
            int   oi = __shfl_xor(bi, off, 64);
            if (ov > bv || (ov == bv && oi < bi)) { bv = ov; bi = oi; }
        }
        // (bv,bi) now uniform across the wave
        if      (bi == i0) { v0 = -__builtin_inff(); i0 = 0x7fffffff; }
        else if (bi == i1) { v1 = -__builtin_inff(); i1 = 0x7fffffff; }
        int safe = bi & (NN - 1);
        if (t == r) out_idx[obase + r] = (float)safe;   // wave 0, lane r
        if ((r & 3) == g) idxs[r >> 2] = safe;          // this wave's rows
    }

    // Gather: wave g handles out rows r = rr*4 + g; 64 lanes x 16 B per row.
#pragma unroll
    for (int rr = 0; rr < 8; ++rr) {
        const int r = rr * 4 + g;
        f32x4 v = *((const f32x4*)(patches + ((size_t)b * NN + idxs[rr]) * ND) + l);
        *((f32x4*)(out_sel + (size_t)(obase + r) * ND) + l) = v;
    }
}

// ---------------------------------------------------------------------------
extern "C" void kernel_launch(void* const* d_in, const int* in_sizes, int n_in,
                              void* d_out, int out_size, void* d_ws, size_t ws_size,
                              hipStream_t stream) {
    const float* patches = (const float*)d_in[0];
    const float* feat    = (const float*)d_in[1];
    const float* W1      = (const float*)d_in[2];
    const float* b1      = (const float*)d_in[3];
    const float* W2      = (const float*)d_in[4];
    const float* b2      = (const float*)d_in[5];
    const float* gum     = (const float*)d_in[6];
    // d_in[7] = lookup: structurally arange(N) % 64 — exploited.

    float* out       = (float*)d_out;
    float* out_sel   = out;                       // 8,388,608 f32
    float* out_idx   = out + 8388608;             // 32,768 f32 (exact ints)
    float* out_logit = out + 8388608 + 32768;     // 131,072 f32

    // scratch aliased into the (not-yet-written) out_sel region
    unsigned short* W1T = (unsigned short*)(out_sel);   // 128 KB, [2][128][256]

    k_prep<<<128, 256, 0, stream>>>(W1, W1T);
    k_mlp<<<(NB * NN) / 128, 256, 0, stream>>>(feat, W1T, b1, W2, b2, out_logit);
    k_topk_gather<<<NB * NPARCEL, 256, 0, stream>>>(out_logit, gum, patches, out_sel, out_idx);
}

// Round 5
// 305.803 us; speedup vs baseline: 1.3283x; 1.0085x over previous
//
#include <hip/hip_runtime.h>
#include <hip/hip_bf16.h>

// Problem constants (B=16, N=8192, D=256, H=128, 64 parcels x top-32)
// Dtype model: inputs FLOAT32, outputs FLOAT32.
//   Output 0: selected_patches f32[16,2048,256]  elements [0, 8388608)
//   Output 1: all_selected_indices -> f32        elements [8388608, 8421376)
//   Output 2: importance_logits f32[16,8192]     elements [8421376, 8552448)
#define NB 16
#define NN 8192
#define ND 256
#define NH 128
#define NPARCEL 64
#define KSEL 32

typedef __attribute__((ext_vector_type(8))) short short8;   // 8 bf16 lanes (4 VGPRs)
typedef __attribute__((ext_vector_type(4))) float floatx4;  // MFMA C/D
typedef __attribute__((ext_vector_type(4))) float f32x4;

// f32 -> bf16 (RNE) bit trick; finite inputs only
__device__ __forceinline__ unsigned short f2b(float x) {
    unsigned u = __builtin_bit_cast(unsigned, x);
    u += 0x7fffu + ((u >> 16) & 1u);
    return (unsigned short)(u >> 16);
}
__device__ __forceinline__ float b2f(unsigned short h) {
    return __builtin_bit_cast(float, (unsigned)h << 16);
}

// ---------------------------------------------------------------------------
// Scratch aliased into out_sel (dead until the fused gather, which is the
// last kernel and overwrites every row):
//   W1S  128 KB = f32 elements [0, 32768) = rows [0, 128)
//     Pre-swizzled phase-major layout: 4 phases x 32 KB. Phase p holds both
//     bf16 planes for k in [p*64, p*64+64):
//       lin  = pl*16384 + h*128 + (k - p*64)*2          (byte, within phase)
//       byte = p*32768 + (lin ^ ((h&7)<<4))             (XOR bank swizzle)
//     k_mlp stages phase p with a LINEAR 16B-chunk copy (swizzle is baked
//     into the data order), and ds_reads with the same XOR -> uniform
//     8 lanes per 16B slot = the wave64 ds_read_b128 optimum.
// The fused top-k recomputes z = logit + gumbel from out_logit (exact f32
// round-trip -> bitwise-identical z) and keeps sel in registers. d_ws unused.

// ---------------------------------------------------------------------------
// Kernel 0: W1 f32 [256,128] -> pre-swizzled split-bf16 phase blob (above).
__global__ __launch_bounds__(256) void k_prep(const float* __restrict__ W1,
                                              unsigned short* __restrict__ W1S) {
    int i = blockIdx.x * 256 + threadIdx.x;   // 32768
    int k = i >> 7;        // 0..255
    int h = i & 127;       // 0..127
    float w = W1[i];
    unsigned short hi = f2b(w);
    unsigned short lo = f2b(w - b2f(hi));
    int p   = k >> 6;
    int kk6 = k & 63;
    int swz = (h & 7) << 4;
    unsigned char* base = (unsigned char*)W1S + p * 32768;
    int linh = h * 128 + kk6 * 2;             // hi plane (pl=0)
    int linl = 16384 + linh;                  // lo plane (pl=1)
    *(unsigned short*)(base + (linh ^ swz)) = hi;
    *(unsigned short*)(base + (linl ^ swz)) = lo;
}

// ---------------------------------------------------------------------------
// Kernel 1: logits = relu(X@W1+b1)@W2+b2 with split-bf16 MFMA (hh+hl+lh),
// ~1e-6-accurate f32 logits (top-k rank stability vs the f32 reference).
//
// Round-4 structure (occupancy x2):
//  - Round 3 (64 KB LDS, 2 phases, A-prefetch): 2 blocks/CU = 2 waves/SIMD.
//    The per-kk serial chain (4 global A loads -> vmcnt -> convert -> MFMA)
//    plus barrier drains can't be hidden by 2 waves -> k_mlp ~60 us vs the
//    ~20 us memory floor.
//  - Now: 4 phases x 32 KB (both planes, 64-k span each), pre-swizzled W1S
//    so staging is a linear coalesced copy; A-prefetch dropped (-16 VGPR);
//    __launch_bounds__(256,4) -> VGPR<=128, 4 blocks/CU (LDS 4x32=128 KB),
//    grid 1024 = exactly 4/CU, one clean block wavefront. Latency hiding
//    moves from in-wave prefetch to 4-wave/SIMD TLP (covers A-load latency,
//    convert chains, and the 8 barrier drains).
//    Live set ~ acc(64)+A(16)+conv(16)+B(8)+addr ~ 114 <= 128 (no spills).
// MFMA order per acc element unchanged (k0 ascending; hh, hl, lh per k0) ->
// bitwise-identical logits to rounds 0/2/3.
__global__ __launch_bounds__(256, 4) void k_mlp(const float* __restrict__ feat,
                                                const unsigned short* __restrict__ W1S,
                                                const float* __restrict__ b1,
                                                const float* __restrict__ W2,
                                                const float* __restrict__ b2,
                                                float* __restrict__ out_logit) {
    __shared__ f32x4 lds4[2048];             // 32 KB, one phase, swizzle baked in
    unsigned char* lds = (unsigned char*)lds4;

    const int tid  = threadIdx.x;
    const int wave = tid >> 6;
    const int lane = tid & 63;
    const int quad = lane >> 4;
    const int m    = lane & 15;
    const int wavebase = blockIdx.x * 128 + wave * 32;

    const float* ap0 = feat + (size_t)(wavebase + m) * ND + quad * 8;
    const float* ap1 = ap0 + 16 * ND;
    const int swz = (m & 7) << 4;            // h&7 == m&7 for h = nt*16+m

    floatx4 acc[2][8];
#pragma unroll
    for (int rg = 0; rg < 2; ++rg)
#pragma unroll
        for (int nt = 0; nt < 8; ++nt) acc[rg][nt] = (floatx4){0.f, 0.f, 0.f, 0.f};

#pragma unroll 1
    for (int p = 0; p < 4; ++p) {
        if (p) __syncthreads();              // all waves done reading phase p-1
        // Linear 32 KB copy: thread t moves chunks t, t+256, ..., t+1792.
        // Consecutive lanes -> consecutive 16B: coalesced global reads,
        // conflict-free consecutive-byte LDS writes.
        const f32x4* src = (const f32x4*)((const unsigned char*)W1S + p * 32768);
#pragma unroll
        for (int i = 0; i < 8; ++i) lds4[tid + i * 256] = src[tid + i * 256];
        __syncthreads();

#pragma unroll 1
        for (int kx = 0; kx < 2; ++kx) {
            const int k0 = p * 64 + kx * 32;
            // A for both rowgroups of this k0 (32 B/lane each)
            f32x4 a00 = *(const f32x4*)(ap0 + k0);
            f32x4 a01 = *(const f32x4*)(ap0 + k0 + 4);
            f32x4 a10 = *(const f32x4*)(ap1 + k0);
            f32x4 a11 = *(const f32x4*)(ap1 + k0 + 4);

            // convert current A to split bf16
            short8 ah0, al0, ah1, al1;
#pragma unroll
            for (int j = 0; j < 8; ++j) {
                float x0 = (j < 4) ? a00[j] : a01[j - 4];
                unsigned short h0 = f2b(x0);
                ah0[j] = (short)h0;
                al0[j] = (short)f2b(x0 - b2f(h0));
                float x1 = (j < 4) ? a10[j] : a11[j - 4];
                unsigned short h1 = f2b(x1);
                ah1[j] = (short)h1;
                al1[j] = (short)f2b(x1 - b2f(h1));
            }

            // B from LDS: h = nt*16 + m; phase row = 128 B; nt*2048 is an
            // immediate and doesn't touch the XOR bits (4..6).
            const int rb = (m * 128 + quad * 16 + kx * 64) ^ swz;
#pragma unroll
            for (int nt = 0; nt < 8; ++nt) {
                short8 bh = *(const short8*)(lds + (rb + nt * 2048));
                short8 bl = *(const short8*)(lds + (rb + nt * 2048 + 16384));
                // per-acc-element order unchanged: hh, hl, lh
                acc[0][nt] = __builtin_amdgcn_mfma_f32_16x16x32_bf16(ah0, bh, acc[0][nt], 0, 0, 0);
                acc[0][nt] = __builtin_amdgcn_mfma_f32_16x16x32_bf16(ah0, bl, acc[0][nt], 0, 0, 0);
                acc[0][nt] = __builtin_amdgcn_mfma_f32_16x16x32_bf16(al0, bh, acc[0][nt], 0, 0, 0);
                acc[1][nt] = __builtin_amdgcn_mfma_f32_16x16x32_bf16(ah1, bh, acc[1][nt], 0, 0, 0);
                acc[1][nt] = __builtin_amdgcn_mfma_f32_16x16x32_bf16(ah1, bl, acc[1][nt], 0, 0, 0);
                acc[1][nt] = __builtin_amdgcn_mfma_f32_16x16x32_bf16(al1, bh, acc[1][nt], 0, 0, 0);
            }
        }
    }

    // Epilogue (f32): relu(acc + b1) * W2, reduce over hidden, + b2.
    const float b2v = b2[0];
#pragma unroll
    for (int rg = 0; rg < 2; ++rg) {
        float s[4] = {0.f, 0.f, 0.f, 0.f};
#pragma unroll
        for (int nt = 0; nt < 8; ++nt) {
            float b1f = b1[nt * 16 + m];
            float w2f = W2[nt * 16 + m];
#pragma unroll
            for (int r = 0; r < 4; ++r) {
                float h = acc[rg][nt][r] + b1f;
                s[r] += (h > 0.f ? h : 0.f) * w2f;
            }
        }
#pragma unroll
        for (int off = 1; off < 16; off <<= 1) {
#pragma unroll
            for (int r = 0; r < 4; ++r) s[r] += __shfl_xor(s[r], off, 64);
        }
        if (m == 0) {
            int rowbase = wavebase + rg * 16 + quad * 4;
#pragma unroll
            for (int r = 0; r < 4; ++r) {
                int row = rowbase + r;
                out_logit[row] = s[r] + b2v;
            }
        }
    }
}

// ---------------------------------------------------------------------------
// Kernel 2 (fused top-k + gather): one block per (batch,parcel).
// z = logit + gumbel is recomputed from out_logit (exact f32 values -> z is
// bitwise-identical; identical top-k ranks). All 4 waves redundantly run the
// 32-round wave-argmax (same result, in parallel on 4 SIMDs, no LDS/sync);
// each wave keeps its 8 row indices in statically-indexed registers, then
// gathers its 8 patch rows. Tie -> smaller index (jax.lax.top_k stable
// order). Indices clamped into [0,8191] so garbage can never fault.
__global__ __launch_bounds__(256) void k_topk_gather(const float* __restrict__ logit,
                                                     const float* __restrict__ gum,
                                                     const float* __restrict__ patches,
                                                     float* __restrict__ out_sel,
                                                     float* __restrict__ out_idx) {
    const int b = blockIdx.x >> 6;
    const int p = blockIdx.x & 63;
    const int t = threadIdx.x;
    const int g = t >> 6;      // wave 0..3
    const int l = t & 63;      // lane

    const float* lb = logit + b * NN;
    const float* gb = gum + b * NN;
    int i0 = p + 64 * l;       // candidate set of parcel p: {p + 64*j, j=0..127}
    int i1 = i0 + 4096;
    float v0 = lb[i0] + gb[i0];
    float v1 = lb[i1] + gb[i1];
    const int obase = b * (NPARCEL * KSEL) + p * KSEL;

    int idxs[8];               // statically indexed (unrolled) -> registers
#pragma unroll
    for (int r = 0; r < KSEL; ++r) {
        float bv; int bi;
        if (v0 > v1 || (v0 == v1 && i0 < i1)) { bv = v0; bi = i0; }
        else                                  { bv = v1; bi = i1; }
#pragma unroll
        for (int off = 1; off < 64; off <<= 1) {
            float ov = __shfl_xor(bv, off, 64);
            int   oi = __shfl_xor(bi, off, 64);
            if (ov > bv || (ov == bv && oi < bi)) { bv = ov; bi = oi; }
        }
        // (bv,bi) now uniform across the wave
        if      (bi == i0) { v0 = -__builtin_inff(); i0 = 0x7fffffff; }
        else if (bi == i1) { v1 = -__builtin_inff(); i1 = 0x7fffffff; }
        int safe = bi & (NN - 1);
        if (t == r) out_idx[obase + r] = (float)safe;   // wave 0, lane r
        if ((r & 3) == g) idxs[r >> 2] = safe;          // this wave's rows
    }

    // Gather: wave g handles out rows r = rr*4 + g; 64 lanes x 16 B per row.
#pragma unroll
    for (int rr = 0; rr < 8; ++rr) {
        const int r = rr * 4 + g;
        f32x4 v = *((const f32x4*)(patches + ((size_t)b * NN + idxs[rr]) * ND) + l);
        *((f32x4*)(out_sel + (size_t)(obase + r) * ND) + l) = v;
    }
}

// ---------------------------------------------------------------------------
extern "C" void kernel_launch(void* const* d_in, const int* in_sizes, int n_in,
                              void* d_out, int out_size, void* d_ws, size_t ws_size,
                              hipStream_t stream) {
    const float* patches = (const float*)d_in[0];
    const float* feat    = (const float*)d_in[1];
    const float* W1      = (const float*)d_in[2];
    const float* b1      = (const float*)d_in[3];
    const float* W2      = (const float*)d_in[4];
    const float* b2      = (const float*)d_in[5];
    const float* gum     = (const float*)d_in[6];
    // d_in[7] = lookup: structurally arange(N) % 64 — exploited.

    float* out       = (float*)d_out;
    float* out_sel   = out;                       // 8,388,608 f32
    float* out_idx   = out + 8388608;             // 32,768 f32 (exact ints)
    float* out_logit = out + 8388608 + 32768;     // 131,072 f32

    // scratch aliased into the (not-yet-written) out_sel region
    unsigned short* W1S = (unsigned short*)(out_sel);   // 128 KB pre-swizzled blob

    k_prep<<<128, 256, 0, stream>>>(W1, W1S);
    k_mlp<<<(NB * NN) / 128, 256, 0, stream>>>(feat, W1S, b1, W2, b2, out_logit);
    k_topk_gather<<<NB * NPARCEL, 256, 0, stream>>>(out_logit, gum, patches, out_sel, out_idx);
}